// Round 5
// baseline (325.953 us; speedup 1.0000x reference)
//
#include <hip/hip_runtime.h>

#define USER_NUM 80000
#define ITEM_NUM 40000
#define NNODE (USER_NUM + ITEM_NUM)
#define EMB 64
#define NB 469            // ceil(NNODE / 256) buckets of 256 rows
#define P1_CHUNK 4096
#define BUCKET_CAP 4096   // LDS staging capacity (avg bucket ~2560, Poisson tail << 4096)

// ===========================================================================
// Build step 1: coarse histogram of row>>8 (LDS-aggregated)
// ===========================================================================
__global__ void bucket_hist_kernel(const int* __restrict__ rows, int* __restrict__ bcounts, int nnz) {
    __shared__ int h[NB];
    for (int i = threadIdx.x; i < NB; i += blockDim.x) h[i] = 0;
    __syncthreads();
    int stride = gridDim.x * blockDim.x;
    for (int i = blockIdx.x * blockDim.x + threadIdx.x; i < nnz; i += stride)
        atomicAdd(&h[rows[i] >> 8], 1);
    __syncthreads();
    for (int i = threadIdx.x; i < NB; i += blockDim.x)
        if (h[i]) atomicAdd(&bcounts[i], h[i]);
}

// ===========================================================================
// Build step 2: exclusive scan of 469 bucket counts (single block)
// ===========================================================================
__global__ void bucket_scan_kernel(const int* __restrict__ bcounts, int* __restrict__ bucket_off,
                                   int* __restrict__ bcursor, int* __restrict__ row_ptr, int nnz) {
    __shared__ int lds[512];
    int t = threadIdx.x;
    int v = (t < NB) ? bcounts[t] : 0;
    lds[t] = v;
    __syncthreads();
    for (int off = 1; off < 512; off <<= 1) {
        int add = (t >= off) ? lds[t - off] : 0;
        __syncthreads();
        lds[t] += add;
        __syncthreads();
    }
    if (t < NB) {
        int ex = lds[t] - v;
        bucket_off[t] = ex;
        bcursor[t]    = ex;
    }
    if (t == 0) { bucket_off[NB] = nnz; row_ptr[NNODE] = nnz; }
}

// ===========================================================================
// Build step 3: bin edges into buckets (one global atomic per block,bucket;
// sequential line-friendly writes). tmp packs {col | row_local<<17, val_bits}.
// ===========================================================================
__global__ void phase1_kernel(const int* __restrict__ rows, const int* __restrict__ cols,
                              const float* __restrict__ vals, int* __restrict__ bcursor,
                              int2* __restrict__ tmp, int nnz) {
    __shared__ int h[NB];
    __shared__ int base[NB];
    int t = threadIdx.x;
    for (int i = t; i < NB; i += 256) h[i] = 0;
    __syncthreads();
    int lo = blockIdx.x * P1_CHUNK;
    int hi = lo + P1_CHUNK; if (hi > nnz) hi = nnz;
    for (int i = lo + t; i < hi; i += 256)
        atomicAdd(&h[rows[i] >> 8], 1);
    __syncthreads();
    for (int i = t; i < NB; i += 256) {
        int c = h[i];
        base[i] = c ? atomicAdd(&bcursor[i], c) : 0;
        h[i] = 0;
    }
    __syncthreads();
    for (int i = lo + t; i < hi; i += 256) {
        int r = rows[i];
        int b = r >> 8;
        int loc = atomicAdd(&h[b], 1);
        tmp[base[b] + loc] = make_int2(cols[i] | ((r & 255) << 17), __float_as_int(vals[i]));
    }
}

// ===========================================================================
// Build step 4: one block per bucket. Stage bucket in LDS, exact per-row
// scan -> row_ptr; per-row insertion sort BY COL (gives all spmm waves a
// monotone col sweep -> narrow L2 working-set band); coalesced write-out.
// ===========================================================================
__global__ void phase2_kernel(const int2* __restrict__ tmp, const int* __restrict__ bucket_off,
                              int* __restrict__ row_ptr, int2* __restrict__ edges) {
    __shared__ int hist[256];
    __shared__ int scan[256];
    __shared__ int cur[256];
    __shared__ int2 buf[BUCKET_CAP];
    int b = blockIdx.x;
    int t = threadIdx.x;
    int row0  = b << 8;
    int nrows = NNODE - row0; if (nrows > 256) nrows = 256;
    int start = bucket_off[b];
    int end   = bucket_off[b + 1];
    int cnt   = end - start;
    hist[t] = 0;
    __syncthreads();
    for (int j = start + t; j < end; j += 256)
        atomicAdd(&hist[tmp[j].x >> 17], 1);
    __syncthreads();
    int v = hist[t];
    scan[t] = v;
    __syncthreads();
    for (int off = 1; off < 256; off <<= 1) {
        int add = (t >= off) ? scan[t - off] : 0;
        __syncthreads();
        scan[t] += add;
        __syncthreads();
    }
    int ex = scan[t] - v;                 // bucket-local exclusive prefix
    if (t < nrows) row_ptr[row0 + t] = start + ex;
    cur[t] = ex;
    __syncthreads();
    if (cnt <= BUCKET_CAP) {
        for (int j = start + t; j < end; j += 256) {
            int2 e  = tmp[j];
            int rl  = e.x >> 17;
            int pos = atomicAdd(&cur[rl], 1);
            buf[pos] = make_int2(e.x & 0x1FFFF, e.y);
        }
        __syncthreads();
        // per-row insertion sort by col (thread t owns row t's segment)
        if (t < nrows) {
            int s = ex, e2 = ex + v;
            for (int a = s + 1; a < e2; ++a) {
                int2 key = buf[a];
                int  q   = a - 1;
                while (q >= s && buf[q].x > key.x) { buf[q + 1] = buf[q]; --q; }
                buf[q + 1] = key;
            }
        }
        __syncthreads();
        for (int j = t; j < cnt; j += 256)
            edges[start + j] = buf[j];
    } else {
        // overflow fallback: direct (unsorted) placement — still correct
        for (int j = start + t; j < end; j += 256) {
            int2 e  = tmp[j];
            int rl  = e.x >> 17;
            int pos = atomicAdd(&cur[rl], 1);
            edges[start + pos] = make_int2(e.x & 0x1FFFF, e.y);
        }
    }
}

// ===========================================================================
// CSR SpMM: one wave per row, lane = emb dim. Unroll 8 (8 gathers in flight),
// rows padded with zero-val dummy edges (col 0 -> hot line). Nontemporal
// stores keep the 60 MB output stream from evicting x out of L2.
// ===========================================================================
template <int LAYER>
__launch_bounds__(256)
__global__ void spmm_kernel(const float* __restrict__ xu, const float* __restrict__ xi,
                            const int* __restrict__ row_ptr, const int2* __restrict__ edges,
                            float* __restrict__ y, float* __restrict__ out) {
    int row  = (blockIdx.x * blockDim.x + threadIdx.x) >> 6;
    int lane = threadIdx.x & 63;
    if (row >= NNODE) return;
    int start = row_ptr[row];
    int end   = row_ptr[row + 1];

    float acc[8];
    #pragma unroll
    for (int u = 0; u < 8; ++u) acc[u] = 0.f;

    for (int base = start; base < end; base += 64) {
        int idx = base + lane;
        int2 e  = (idx < end) ? edges[idx] : make_int2(0, 0);  // val bits 0 -> 0.0f
        int cnt = end - base; if (cnt > 64) cnt = 64;
        int cnt_pad = (cnt + 7) & ~7;
        #pragma nounroll
        for (int j = 0; j < cnt_pad; j += 8) {
            float g[8], vv[8];
            #pragma unroll
            for (int u = 0; u < 8; ++u) {
                int   c = __builtin_amdgcn_readlane(e.x, j + u);
                vv[u]   = __int_as_float(__builtin_amdgcn_readlane(e.y, j + u));
                const float* p;
                if (LAYER == 1)
                    p = (c < USER_NUM) ? xu + (size_t)c * EMB : xi + (size_t)(c - USER_NUM) * EMB;
                else
                    p = xu + (size_t)c * EMB;
                g[u] = p[lane];
            }
            #pragma unroll
            for (int u = 0; u < 8; ++u) acc[u] += vv[u] * g[u];
        }
    }

    float s0 = ((acc[0] + acc[1]) + (acc[2] + acc[3])) + ((acc[4] + acc[5]) + (acc[6] + acc[7]));
    size_t o = (size_t)row * EMB + lane;
    if (LAYER == 1) {
        __builtin_nontemporal_store(s0, &y[o]);
        __builtin_nontemporal_store(s0, &out[o]);
    } else if (LAYER == 2) {
        __builtin_nontemporal_store(s0, &y[o]);
        float ov = out[o];
        __builtin_nontemporal_store(ov + s0, &out[o]);
    } else {
        float ov = out[o];
        __builtin_nontemporal_store((ov + s0) * (1.0f / 3.0f), &out[o]);
    }
}

// ===========================================================================
// Fallback (atomic path) in case ws_size is too small for CSR arrays
// ===========================================================================
__global__ void init_kernel(const float* __restrict__ user_emb, const float* __restrict__ item_emb,
                            float* __restrict__ x, float* __restrict__ out) {
    int idx = blockIdx.x * blockDim.x + threadIdx.x;
    const int total = NNODE * EMB / 4;
    if (idx >= total) return;
    const int user_total = USER_NUM * EMB / 4;
    float4 v = (idx < user_total) ? ((const float4*)user_emb)[idx]
                                  : ((const float4*)item_emb)[idx - user_total];
    ((float4*)x)[idx]   = v;
    ((float4*)out)[idx] = make_float4(0.f, 0.f, 0.f, 0.f);
}

__global__ void scatter_kernel(const float* __restrict__ x, float* __restrict__ y,
                               const float* __restrict__ vals, const int* __restrict__ rows,
                               const int* __restrict__ cols, int nnz) {
    int tid = blockIdx.x * blockDim.x + threadIdx.x;
    int e = tid >> 4;
    if (e >= nnz) return;
    int c = tid & 15;
    int r = rows[e], col = cols[e];
    float v = vals[e];
    float4 xv = ((const float4*)(x + (size_t)col * EMB))[c];
    float* dst = y + (size_t)r * EMB + (size_t)c * 4;
    atomicAdd(dst + 0, xv.x * v);
    atomicAdd(dst + 1, xv.y * v);
    atomicAdd(dst + 2, xv.z * v);
    atomicAdd(dst + 3, xv.w * v);
}

__global__ void accum_kernel(float* __restrict__ out, const float* __restrict__ y, float scale) {
    int idx = blockIdx.x * blockDim.x + threadIdx.x;
    const int total = NNODE * EMB / 4;
    if (idx >= total) return;
    float4 o = ((float4*)out)[idx];
    float4 a = ((const float4*)y)[idx];
    o.x = (o.x + a.x) * scale; o.y = (o.y + a.y) * scale;
    o.z = (o.z + a.z) * scale; o.w = (o.w + a.w) * scale;
    ((float4*)out)[idx] = o;
}

extern "C" void kernel_launch(void* const* d_in, const int* in_sizes, int n_in,
                              void* d_out, int out_size, void* d_ws, size_t ws_size,
                              hipStream_t stream) {
    const float* user_emb = (const float*)d_in[0];
    const float* item_emb = (const float*)d_in[1];
    const float* vals     = (const float*)d_in[2];
    const int*   rows     = (const int*)d_in[3];
    const int*   cols     = (const int*)d_in[4];
    const int    nnz      = in_sizes[2];

    float* out = (float*)d_out;

    const size_t embN   = (size_t)NNODE * EMB;        // 7,680,000 floats
    const size_t rp_pad = 120064;                     // NNODE+1 rounded up (8B-align after)

    // Persistent ws layout:
    //   bufA: embN floats | bufB: embN floats | row_ptr: rp_pad ints | edges: nnz int2
    // Build-time aliases (dead before their host buffer is written):
    //   tmp (nnz int2) -> front of bufA; bcounts/bucket_off/bcursor -> front of bufB
    size_t need = (2 * embN + rp_pad) * 4 + (size_t)nnz * 8;

    if (ws_size >= need) {
        float* bufA    = (float*)d_ws;
        float* bufB    = bufA + embN;
        int*   row_ptr = (int*)(bufB + embN);
        int2*  edges   = (int2*)(row_ptr + rp_pad);

        int2* tmp        = (int2*)bufA;
        int*  bcounts    = (int*)bufB;
        int*  bucket_off = bcounts + 512;       // NB+1 used
        int*  bcursor    = bucket_off + 512;

        // --- build CSR (two-pass LDS-binned counting sort, col-sorted rows) ---
        hipMemsetAsync(bcounts, 0, NB * sizeof(int), stream);
        bucket_hist_kernel<<<256, 256, 0, stream>>>(rows, bcounts, nnz);
        bucket_scan_kernel<<<1, 512, 0, stream>>>(bcounts, bucket_off, bcursor, row_ptr, nnz);
        phase1_kernel<<<(nnz + P1_CHUNK - 1) / P1_CHUNK, 256, 0, stream>>>(rows, cols, vals, bcursor, tmp, nnz);
        phase2_kernel<<<NB, 256, 0, stream>>>(tmp, bucket_off, row_ptr, edges);

        // --- 3 propagation layers, accumulation fused into epilogues ---
        const int blocks = (NNODE + 3) / 4;   // 4 waves (rows) per 256-thread block
        spmm_kernel<1><<<blocks, 256, 0, stream>>>(user_emb, item_emb, row_ptr, edges, bufA, out);
        spmm_kernel<2><<<blocks, 256, 0, stream>>>(bufA, nullptr, row_ptr, edges, bufB, out);
        spmm_kernel<3><<<blocks, 256, 0, stream>>>(bufB, nullptr, row_ptr, edges, nullptr, out);
    } else {
        // fallback: atomic scatter path
        float* x = (float*)d_ws;
        float* y = x + embN;
        const size_t emb_bytes = embN * sizeof(float);
        {
            int total = NNODE * EMB / 4;
            init_kernel<<<(total + 255) / 256, 256, 0, stream>>>(user_emb, item_emb, x, out);
        }
        for (int layer = 0; layer < 3; ++layer) {
            hipMemsetAsync(y, 0, emb_bytes, stream);
            long long threads = (long long)nnz * 16;
            scatter_kernel<<<(int)((threads + 255) / 256), 256, 0, stream>>>(x, y, vals, rows, cols, nnz);
            int total = NNODE * EMB / 4;
            accum_kernel<<<(total + 255) / 256, 256, 0, stream>>>(out, y, layer < 2 ? 1.0f : (1.0f / 3.0f));
            float* t = x; x = y; y = t;
        }
    }
}

// Round 6
// 303.346 us; speedup vs baseline: 1.0745x; 1.0745x over previous
//
#include <hip/hip_runtime.h>

#define USER_NUM 80000
#define ITEM_NUM 40000
#define NNODE (USER_NUM + ITEM_NUM)
#define EMB 64
#define NB 469            // ceil(NNODE / 256) buckets of 256 rows
#define P1_CHUNK 4096

// ===========================================================================
// Build step 1: coarse histogram of row>>8 (LDS-aggregated)
// ===========================================================================
__global__ void bucket_hist_kernel(const int* __restrict__ rows, int* __restrict__ bcounts, int nnz) {
    __shared__ int h[NB];
    for (int i = threadIdx.x; i < NB; i += blockDim.x) h[i] = 0;
    __syncthreads();
    int stride = gridDim.x * blockDim.x;
    for (int i = blockIdx.x * blockDim.x + threadIdx.x; i < nnz; i += stride)
        atomicAdd(&h[rows[i] >> 8], 1);
    __syncthreads();
    for (int i = threadIdx.x; i < NB; i += blockDim.x)
        if (h[i]) atomicAdd(&bcounts[i], h[i]);
}

// ===========================================================================
// Build step 2: exclusive scan of 469 bucket counts (single block)
// ===========================================================================
__global__ void bucket_scan_kernel(const int* __restrict__ bcounts, int* __restrict__ bucket_off,
                                   int* __restrict__ bcursor, int* __restrict__ row_ptr, int nnz) {
    __shared__ int lds[512];
    int t = threadIdx.x;
    int v = (t < NB) ? bcounts[t] : 0;
    lds[t] = v;
    __syncthreads();
    for (int off = 1; off < 512; off <<= 1) {
        int add = (t >= off) ? lds[t - off] : 0;
        __syncthreads();
        lds[t] += add;
        __syncthreads();
    }
    if (t < NB) {
        int ex = lds[t] - v;
        bucket_off[t] = ex;
        bcursor[t]    = ex;
    }
    if (t == 0) { bucket_off[NB] = nnz; row_ptr[NNODE] = nnz; }
}

// ===========================================================================
// Build step 3: bin edges into buckets (one global atomic per block,bucket;
// sequential line-friendly writes). tmp packs {col | row_local<<17, val_bits}.
// ===========================================================================
__global__ void phase1_kernel(const int* __restrict__ rows, const int* __restrict__ cols,
                              const float* __restrict__ vals, int* __restrict__ bcursor,
                              int2* __restrict__ tmp, int nnz) {
    __shared__ int h[NB];
    __shared__ int base[NB];
    int t = threadIdx.x;
    for (int i = t; i < NB; i += 256) h[i] = 0;
    __syncthreads();
    int lo = blockIdx.x * P1_CHUNK;
    int hi = lo + P1_CHUNK; if (hi > nnz) hi = nnz;
    for (int i = lo + t; i < hi; i += 256)
        atomicAdd(&h[rows[i] >> 8], 1);
    __syncthreads();
    for (int i = t; i < NB; i += 256) {
        int c = h[i];
        base[i] = c ? atomicAdd(&bcursor[i], c) : 0;
        h[i] = 0;
    }
    __syncthreads();
    for (int i = lo + t; i < hi; i += 256) {
        int r = rows[i];
        int b = r >> 8;
        int loc = atomicAdd(&h[b], 1);
        tmp[base[b] + loc] = make_int2(cols[i] | ((r & 255) << 17), __float_as_int(vals[i]));
    }
}

// ===========================================================================
// Build step 4 (R4 version — no sort): one block per bucket, exact per-row
// counts + scan -> row_ptr; LDS cursors place edges into final CSR.
// ===========================================================================
__global__ void phase2_kernel(const int2* __restrict__ tmp, const int* __restrict__ bucket_off,
                              int* __restrict__ row_ptr, int2* __restrict__ edges) {
    __shared__ int hist[256];
    __shared__ int scan[256];
    __shared__ int cur[256];
    int b = blockIdx.x;
    int t = threadIdx.x;
    int row0  = b << 8;
    int nrows = NNODE - row0; if (nrows > 256) nrows = 256;
    int start = bucket_off[b];
    int end   = bucket_off[b + 1];
    hist[t] = 0;
    __syncthreads();
    for (int j = start + t; j < end; j += 256)
        atomicAdd(&hist[tmp[j].x >> 17], 1);
    __syncthreads();
    int v = hist[t];
    scan[t] = v;
    __syncthreads();
    for (int off = 1; off < 256; off <<= 1) {
        int add = (t >= off) ? scan[t - off] : 0;
        __syncthreads();
        scan[t] += add;
        __syncthreads();
    }
    int ex = scan[t] - v + start;   // exclusive prefix + bucket base
    if (t < nrows) row_ptr[row0 + t] = ex;
    cur[t] = ex;
    __syncthreads();
    for (int j = start + t; j < end; j += 256) {
        int2 e  = tmp[j];
        int rl  = e.x >> 17;
        int pos = atomicAdd(&cur[rl], 1);
        edges[pos] = make_int2(e.x & 0x1FFFF, e.y);
    }
}

// ===========================================================================
// CSR SpMM: 4 rows per wave, lane = emb dim. The 4 rows' edges form one
// contiguous segment (avg ~40 edges). Batches of 8 independent gathers;
// accumulator picked per edge by wave-uniform SCALAR branches (row boundaries
// broadcast to SGPRs via readlane). Pads are zero-val edges -> contribute 0.
// ===========================================================================
template <int LAYER>
__launch_bounds__(256)
__global__ void spmm_kernel(const float* __restrict__ xu, const float* __restrict__ xi,
                            const int* __restrict__ row_ptr, const int2* __restrict__ edges,
                            float* __restrict__ y, float* __restrict__ out) {
    int wave = (blockIdx.x * blockDim.x + threadIdx.x) >> 6;
    int lane = threadIdx.x & 63;
    int r0 = wave << 2;                    // 4 rows per wave; NNODE % 4 == 0
    if (r0 >= NNODE) return;

    int rp = 0;
    if (lane < 5) rp = row_ptr[r0 + lane];
    int start = __builtin_amdgcn_readlane(rp, 0);
    int b1    = __builtin_amdgcn_readlane(rp, 1);
    int b2    = __builtin_amdgcn_readlane(rp, 2);
    int b3    = __builtin_amdgcn_readlane(rp, 3);
    int end   = __builtin_amdgcn_readlane(rp, 4);

    float a0 = 0.f, a1 = 0.f, a2 = 0.f, a3 = 0.f;

    for (int base = start; base < end; base += 64) {
        int idx = base + lane;
        int2 e  = (idx < end) ? edges[idx] : make_int2(0, 0);  // val bits 0 -> 0.0f
        int cnt = end - base; if (cnt > 64) cnt = 64;
        int cnt_pad = (cnt + 7) & ~7;
        #pragma nounroll
        for (int j = 0; j < cnt_pad; j += 8) {
            float g[8], vv[8];
            #pragma unroll
            for (int u = 0; u < 8; ++u) {
                int   c = __builtin_amdgcn_readlane(e.x, j + u);
                vv[u]   = __int_as_float(__builtin_amdgcn_readlane(e.y, j + u));
                const float* p;
                if (LAYER == 1)
                    p = (c < USER_NUM) ? xu + (size_t)c * EMB : xi + (size_t)(c - USER_NUM) * EMB;
                else
                    p = xu + (size_t)c * EMB;
                g[u] = p[lane];
            }
            #pragma unroll
            for (int u = 0; u < 8; ++u) {
                int   idx2 = base + j + u;   // wave-uniform (SGPR) edge index
                float vg   = vv[u] * g[u];
                if (idx2 < b1)      a0 += vg;
                else if (idx2 < b2) a1 += vg;
                else if (idx2 < b3) a2 += vg;
                else                a3 += vg;   // pads land here with vg == 0
            }
        }
    }

    size_t o = (size_t)r0 * EMB + lane;
    if (LAYER == 1) {
        y[o]       = a0;  y[o + 64]  = a1;  y[o + 128] = a2;  y[o + 192] = a3;
        out[o]     = a0;  out[o + 64] = a1; out[o + 128] = a2; out[o + 192] = a3;
    } else if (LAYER == 2) {
        y[o]       = a0;  y[o + 64]  = a1;  y[o + 128] = a2;  y[o + 192] = a3;
        out[o]    += a0;  out[o + 64] += a1; out[o + 128] += a2; out[o + 192] += a3;
    } else {
        const float s = 1.0f / 3.0f;
        out[o]       = (out[o]       + a0) * s;
        out[o + 64]  = (out[o + 64]  + a1) * s;
        out[o + 128] = (out[o + 128] + a2) * s;
        out[o + 192] = (out[o + 192] + a3) * s;
    }
}

// ===========================================================================
// Fallback (atomic path) in case ws_size is too small for CSR arrays
// ===========================================================================
__global__ void init_kernel(const float* __restrict__ user_emb, const float* __restrict__ item_emb,
                            float* __restrict__ x, float* __restrict__ out) {
    int idx = blockIdx.x * blockDim.x + threadIdx.x;
    const int total = NNODE * EMB / 4;
    if (idx >= total) return;
    const int user_total = USER_NUM * EMB / 4;
    float4 v = (idx < user_total) ? ((const float4*)user_emb)[idx]
                                  : ((const float4*)item_emb)[idx - user_total];
    ((float4*)x)[idx]   = v;
    ((float4*)out)[idx] = make_float4(0.f, 0.f, 0.f, 0.f);
}

__global__ void scatter_kernel(const float* __restrict__ x, float* __restrict__ y,
                               const float* __restrict__ vals, const int* __restrict__ rows,
                               const int* __restrict__ cols, int nnz) {
    int tid = blockIdx.x * blockDim.x + threadIdx.x;
    int e = tid >> 4;
    if (e >= nnz) return;
    int c = tid & 15;
    int r = rows[e], col = cols[e];
    float v = vals[e];
    float4 xv = ((const float4*)(x + (size_t)col * EMB))[c];
    float* dst = y + (size_t)r * EMB + (size_t)c * 4;
    atomicAdd(dst + 0, xv.x * v);
    atomicAdd(dst + 1, xv.y * v);
    atomicAdd(dst + 2, xv.z * v);
    atomicAdd(dst + 3, xv.w * v);
}

__global__ void accum_kernel(float* __restrict__ out, const float* __restrict__ y, float scale) {
    int idx = blockIdx.x * blockDim.x + threadIdx.x;
    const int total = NNODE * EMB / 4;
    if (idx >= total) return;
    float4 o = ((float4*)out)[idx];
    float4 a = ((const float4*)y)[idx];
    o.x = (o.x + a.x) * scale; o.y = (o.y + a.y) * scale;
    o.z = (o.z + a.z) * scale; o.w = (o.w + a.w) * scale;
    ((float4*)out)[idx] = o;
}

extern "C" void kernel_launch(void* const* d_in, const int* in_sizes, int n_in,
                              void* d_out, int out_size, void* d_ws, size_t ws_size,
                              hipStream_t stream) {
    const float* user_emb = (const float*)d_in[0];
    const float* item_emb = (const float*)d_in[1];
    const float* vals     = (const float*)d_in[2];
    const int*   rows     = (const int*)d_in[3];
    const int*   cols     = (const int*)d_in[4];
    const int    nnz      = in_sizes[2];

    float* out = (float*)d_out;

    const size_t embN   = (size_t)NNODE * EMB;        // 7,680,000 floats
    const size_t rp_pad = 120064;                     // NNODE+1 rounded up (8B-align after)

    // Persistent ws layout:
    //   bufA: embN floats | bufB: embN floats | row_ptr: rp_pad ints | edges: nnz int2
    // Build-time aliases (dead before their host buffer is written):
    //   tmp (nnz int2) -> front of bufA; bcounts/bucket_off/bcursor -> front of bufB
    size_t need = (2 * embN + rp_pad) * 4 + (size_t)nnz * 8;

    if (ws_size >= need) {
        float* bufA    = (float*)d_ws;
        float* bufB    = bufA + embN;
        int*   row_ptr = (int*)(bufB + embN);
        int2*  edges   = (int2*)(row_ptr + rp_pad);

        int2* tmp        = (int2*)bufA;
        int*  bcounts    = (int*)bufB;
        int*  bucket_off = bcounts + 512;       // NB+1 used
        int*  bcursor    = bucket_off + 512;

        // --- build CSR (two-pass LDS-binned counting sort) ---
        hipMemsetAsync(bcounts, 0, NB * sizeof(int), stream);
        bucket_hist_kernel<<<256, 256, 0, stream>>>(rows, bcounts, nnz);
        bucket_scan_kernel<<<1, 512, 0, stream>>>(bcounts, bucket_off, bcursor, row_ptr, nnz);
        phase1_kernel<<<(nnz + P1_CHUNK - 1) / P1_CHUNK, 256, 0, stream>>>(rows, cols, vals, bcursor, tmp, nnz);
        phase2_kernel<<<NB, 256, 0, stream>>>(tmp, bucket_off, row_ptr, edges);

        // --- 3 propagation layers, accumulation fused into epilogues ---
        const int nwaves = NNODE / 4;                      // 4 rows per wave
        const int blocks = (nwaves * 64 + 255) / 256;      // 4 waves per block
        spmm_kernel<1><<<blocks, 256, 0, stream>>>(user_emb, item_emb, row_ptr, edges, bufA, out);
        spmm_kernel<2><<<blocks, 256, 0, stream>>>(bufA, nullptr, row_ptr, edges, bufB, out);
        spmm_kernel<3><<<blocks, 256, 0, stream>>>(bufB, nullptr, row_ptr, edges, nullptr, out);
    } else {
        // fallback: atomic scatter path
        float* x = (float*)d_ws;
        float* y = x + embN;
        const size_t emb_bytes = embN * sizeof(float);
        {
            int total = NNODE * EMB / 4;
            init_kernel<<<(total + 255) / 256, 256, 0, stream>>>(user_emb, item_emb, x, out);
        }
        for (int layer = 0; layer < 3; ++layer) {
            hipMemsetAsync(y, 0, emb_bytes, stream);
            long long threads = (long long)nnz * 16;
            scatter_kernel<<<(int)((threads + 255) / 256), 256, 0, stream>>>(x, y, vals, rows, cols, nnz);
            int total = NNODE * EMB / 4;
            accum_kernel<<<(total + 255) / 256, 256, 0, stream>>>(out, y, layer < 2 ? 1.0f : (1.0f / 3.0f));
            float* t = x; x = y; y = t;
        }
    }
}

// Round 7
// 296.421 us; speedup vs baseline: 1.0996x; 1.0234x over previous
//
#include <hip/hip_runtime.h>

#define USER_NUM 80000
#define ITEM_NUM 40000
#define NNODE (USER_NUM + ITEM_NUM)
#define EMB 64
#define NB 469            // ceil(NNODE / 256) buckets of 256 rows
#define P1_CHUNK 4096

// ===========================================================================
// Build step 1: coarse histogram of row>>8 (LDS-aggregated)
// ===========================================================================
__global__ void bucket_hist_kernel(const int* __restrict__ rows, int* __restrict__ bcounts, int nnz) {
    __shared__ int h[NB];
    for (int i = threadIdx.x; i < NB; i += blockDim.x) h[i] = 0;
    __syncthreads();
    int stride = gridDim.x * blockDim.x;
    for (int i = blockIdx.x * blockDim.x + threadIdx.x; i < nnz; i += stride)
        atomicAdd(&h[rows[i] >> 8], 1);
    __syncthreads();
    for (int i = threadIdx.x; i < NB; i += blockDim.x)
        if (h[i]) atomicAdd(&bcounts[i], h[i]);
}

// ===========================================================================
// Build step 2: exclusive scan of 469 bucket counts (single block)
// ===========================================================================
__global__ void bucket_scan_kernel(const int* __restrict__ bcounts, int* __restrict__ bucket_off,
                                   int* __restrict__ bcursor, int* __restrict__ row_ptr, int nnz) {
    __shared__ int lds[512];
    int t = threadIdx.x;
    int v = (t < NB) ? bcounts[t] : 0;
    lds[t] = v;
    __syncthreads();
    for (int off = 1; off < 512; off <<= 1) {
        int add = (t >= off) ? lds[t - off] : 0;
        __syncthreads();
        lds[t] += add;
        __syncthreads();
    }
    if (t < NB) {
        int ex = lds[t] - v;
        bucket_off[t] = ex;
        bcursor[t]    = ex;
    }
    if (t == 0) { bucket_off[NB] = nnz; row_ptr[NNODE] = nnz; }
}

// ===========================================================================
// Build step 3: bin edges into buckets (one global atomic per block,bucket;
// sequential line-friendly writes). tmp packs {col | row_local<<17, val_bits}.
// ===========================================================================
__global__ void phase1_kernel(const int* __restrict__ rows, const int* __restrict__ cols,
                              const float* __restrict__ vals, int* __restrict__ bcursor,
                              int2* __restrict__ tmp, int nnz) {
    __shared__ int h[NB];
    __shared__ int base[NB];
    int t = threadIdx.x;
    for (int i = t; i < NB; i += 256) h[i] = 0;
    __syncthreads();
    int lo = blockIdx.x * P1_CHUNK;
    int hi = lo + P1_CHUNK; if (hi > nnz) hi = nnz;
    for (int i = lo + t; i < hi; i += 256)
        atomicAdd(&h[rows[i] >> 8], 1);
    __syncthreads();
    for (int i = t; i < NB; i += 256) {
        int c = h[i];
        base[i] = c ? atomicAdd(&bcursor[i], c) : 0;
        h[i] = 0;
    }
    __syncthreads();
    for (int i = lo + t; i < hi; i += 256) {
        int r = rows[i];
        int b = r >> 8;
        int loc = atomicAdd(&h[b], 1);
        tmp[base[b] + loc] = make_int2(cols[i] | ((r & 255) << 17), __float_as_int(vals[i]));
    }
}

// ===========================================================================
// Build step 4: one block per bucket, exact per-row counts + scan -> row_ptr;
// LDS cursors place edges into final CSR.
// ===========================================================================
__global__ void phase2_kernel(const int2* __restrict__ tmp, const int* __restrict__ bucket_off,
                              int* __restrict__ row_ptr, int2* __restrict__ edges) {
    __shared__ int hist[256];
    __shared__ int scan[256];
    __shared__ int cur[256];
    int b = blockIdx.x;
    int t = threadIdx.x;
    int row0  = b << 8;
    int nrows = NNODE - row0; if (nrows > 256) nrows = 256;
    int start = bucket_off[b];
    int end   = bucket_off[b + 1];
    hist[t] = 0;
    __syncthreads();
    for (int j = start + t; j < end; j += 256)
        atomicAdd(&hist[tmp[j].x >> 17], 1);
    __syncthreads();
    int v = hist[t];
    scan[t] = v;
    __syncthreads();
    for (int off = 1; off < 256; off <<= 1) {
        int add = (t >= off) ? scan[t - off] : 0;
        __syncthreads();
        scan[t] += add;
        __syncthreads();
    }
    int ex = scan[t] - v + start;   // exclusive prefix + bucket base
    if (t < nrows) row_ptr[row0 + t] = ex;
    cur[t] = ex;
    __syncthreads();
    for (int j = start + t; j < end; j += 256) {
        int2 e  = tmp[j];
        int rl  = e.x >> 17;
        int pos = atomicAdd(&cur[rl], 1);
        edges[pos] = make_int2(e.x & 0x1FFFF, e.y);
    }
}

// ===========================================================================
// CSR SpMM, lane remap: wave owns 4 rows; lane group g (16 lanes) owns row
// r0+g; lane c=(lane&15) holds dims [4c,4c+4). Per iteration each lane loads
// its row's next edge (int2, per-lane -> NO readlane broadcasts) then one
// dwordx4 gather: 1 KB / instruction = 4 edges. Short rows padded to the
// wave max degree with clamped-address, zero-val dummies (uniform loop).
// Epilogue: coalesced float4 stores, no cross-lane reduction.
// ===========================================================================
template <int LAYER>
__launch_bounds__(256)
__global__ void spmm_kernel(const float* __restrict__ xu, const float* __restrict__ xi,
                            const int* __restrict__ row_ptr, const int2* __restrict__ edges,
                            float* __restrict__ y, float* __restrict__ out) {
    int wave = (blockIdx.x * blockDim.x + threadIdx.x) >> 6;
    int lane = threadIdx.x & 63;
    int r0 = wave << 2;                    // 4 rows per wave; NNODE % 4 == 0
    if (r0 >= NNODE) return;
    int g = lane >> 4;                     // which of the 4 rows
    int c = lane & 15;                     // which float4 chunk of the row

    int rp = 0;
    if (lane < 5) rp = row_ptr[r0 + lane];
    int p0 = __builtin_amdgcn_readlane(rp, 0);
    int p1 = __builtin_amdgcn_readlane(rp, 1);
    int p2 = __builtin_amdgcn_readlane(rp, 2);
    int p3 = __builtin_amdgcn_readlane(rp, 3);
    int p4 = __builtin_amdgcn_readlane(rp, 4);

    int sg = (g == 0) ? p0 : (g == 1) ? p1 : (g == 2) ? p2 : p3;   // row start
    int eg = (g == 0) ? p1 : (g == 1) ? p2 : (g == 2) ? p3 : p4;   // row end
    int maxd = max(max(p1 - p0, p2 - p1), max(p3 - p2, p4 - p3));  // wave loop bound

    float4 acc = make_float4(0.f, 0.f, 0.f, 0.f);

    for (int j = 0; j < maxd; j += 2) {
        int i0 = sg + j;
        int i1 = i0 + 1;
        int k0 = max(min(i0, eg - 1), 0);      // clamp: dummy reads last valid edge
        int k1 = max(min(i1, eg - 1), 0);
        int2 e0 = edges[k0];
        int2 e1 = edges[k1];
        float v0 = (i0 < eg) ? __int_as_float(e0.y) : 0.f;
        float v1 = (i1 < eg) ? __int_as_float(e1.y) : 0.f;
        const float *q0, *q1;
        if (LAYER == 1) {
            q0 = (e0.x < USER_NUM) ? xu + (size_t)e0.x * EMB : xi + (size_t)(e0.x - USER_NUM) * EMB;
            q1 = (e1.x < USER_NUM) ? xu + (size_t)e1.x * EMB : xi + (size_t)(e1.x - USER_NUM) * EMB;
        } else {
            q0 = xu + (size_t)e0.x * EMB;
            q1 = xu + (size_t)e1.x * EMB;
        }
        float4 g0 = ((const float4*)q0)[c];
        float4 g1 = ((const float4*)q1)[c];
        acc.x += v0 * g0.x; acc.y += v0 * g0.y; acc.z += v0 * g0.z; acc.w += v0 * g0.w;
        acc.x += v1 * g1.x; acc.y += v1 * g1.y; acc.z += v1 * g1.z; acc.w += v1 * g1.w;
    }

    size_t o = (size_t)(r0 + g) * EMB + (size_t)c * 4;
    float4* yp = (float4*)(y + o);
    float4* op = (float4*)(out + o);
    if (LAYER == 1) {
        *yp = acc;
        *op = acc;
    } else if (LAYER == 2) {
        *yp = acc;
        float4 t = *op;
        t.x += acc.x; t.y += acc.y; t.z += acc.z; t.w += acc.w;
        *op = t;
    } else {
        const float s = 1.0f / 3.0f;
        float4 t = *op;
        t.x = (t.x + acc.x) * s; t.y = (t.y + acc.y) * s;
        t.z = (t.z + acc.z) * s; t.w = (t.w + acc.w) * s;
        *op = t;
    }
}

// ===========================================================================
// Fallback (atomic path) in case ws_size is too small for CSR arrays
// ===========================================================================
__global__ void init_kernel(const float* __restrict__ user_emb, const float* __restrict__ item_emb,
                            float* __restrict__ x, float* __restrict__ out) {
    int idx = blockIdx.x * blockDim.x + threadIdx.x;
    const int total = NNODE * EMB / 4;
    if (idx >= total) return;
    const int user_total = USER_NUM * EMB / 4;
    float4 v = (idx < user_total) ? ((const float4*)user_emb)[idx]
                                  : ((const float4*)item_emb)[idx - user_total];
    ((float4*)x)[idx]   = v;
    ((float4*)out)[idx] = make_float4(0.f, 0.f, 0.f, 0.f);
}

__global__ void scatter_kernel(const float* __restrict__ x, float* __restrict__ y,
                               const float* __restrict__ vals, const int* __restrict__ rows,
                               const int* __restrict__ cols, int nnz) {
    int tid = blockIdx.x * blockDim.x + threadIdx.x;
    int e = tid >> 4;
    if (e >= nnz) return;
    int c = tid & 15;
    int r = rows[e], col = cols[e];
    float v = vals[e];
    float4 xv = ((const float4*)(x + (size_t)col * EMB))[c];
    float* dst = y + (size_t)r * EMB + (size_t)c * 4;
    atomicAdd(dst + 0, xv.x * v);
    atomicAdd(dst + 1, xv.y * v);
    atomicAdd(dst + 2, xv.z * v);
    atomicAdd(dst + 3, xv.w * v);
}

__global__ void accum_kernel(float* __restrict__ out, const float* __restrict__ y, float scale) {
    int idx = blockIdx.x * blockDim.x + threadIdx.x;
    const int total = NNODE * EMB / 4;
    if (idx >= total) return;
    float4 o = ((float4*)out)[idx];
    float4 a = ((const float4*)y)[idx];
    o.x = (o.x + a.x) * scale; o.y = (o.y + a.y) * scale;
    o.z = (o.z + a.z) * scale; o.w = (o.w + a.w) * scale;
    ((float4*)out)[idx] = o;
}

extern "C" void kernel_launch(void* const* d_in, const int* in_sizes, int n_in,
                              void* d_out, int out_size, void* d_ws, size_t ws_size,
                              hipStream_t stream) {
    const float* user_emb = (const float*)d_in[0];
    const float* item_emb = (const float*)d_in[1];
    const float* vals     = (const float*)d_in[2];
    const int*   rows     = (const int*)d_in[3];
    const int*   cols     = (const int*)d_in[4];
    const int    nnz      = in_sizes[2];

    float* out = (float*)d_out;

    const size_t embN   = (size_t)NNODE * EMB;        // 7,680,000 floats
    const size_t rp_pad = 120064;                     // NNODE+1 rounded up (8B-align after)

    // Persistent ws layout:
    //   bufA: embN floats | bufB: embN floats | row_ptr: rp_pad ints | edges: nnz int2
    // Build-time aliases (dead before their host buffer is written):
    //   tmp (nnz int2) -> front of bufA; bcounts/bucket_off/bcursor -> front of bufB
    size_t need = (2 * embN + rp_pad) * 4 + (size_t)nnz * 8;

    if (ws_size >= need) {
        float* bufA    = (float*)d_ws;
        float* bufB    = bufA + embN;
        int*   row_ptr = (int*)(bufB + embN);
        int2*  edges   = (int2*)(row_ptr + rp_pad);

        int2* tmp        = (int2*)bufA;
        int*  bcounts    = (int*)bufB;
        int*  bucket_off = bcounts + 512;       // NB+1 used
        int*  bcursor    = bucket_off + 512;

        // --- build CSR (two-pass LDS-binned counting sort) ---
        hipMemsetAsync(bcounts, 0, NB * sizeof(int), stream);
        bucket_hist_kernel<<<256, 256, 0, stream>>>(rows, bcounts, nnz);
        bucket_scan_kernel<<<1, 512, 0, stream>>>(bcounts, bucket_off, bcursor, row_ptr, nnz);
        phase1_kernel<<<(nnz + P1_CHUNK - 1) / P1_CHUNK, 256, 0, stream>>>(rows, cols, vals, bcursor, tmp, nnz);
        phase2_kernel<<<NB, 256, 0, stream>>>(tmp, bucket_off, row_ptr, edges);

        // --- 3 propagation layers, accumulation fused into epilogues ---
        const int nwaves = NNODE / 4;                      // 4 rows per wave
        const int blocks = (nwaves * 64 + 255) / 256;      // 4 waves per block
        spmm_kernel<1><<<blocks, 256, 0, stream>>>(user_emb, item_emb, row_ptr, edges, bufA, out);
        spmm_kernel<2><<<blocks, 256, 0, stream>>>(bufA, nullptr, row_ptr, edges, bufB, out);
        spmm_kernel<3><<<blocks, 256, 0, stream>>>(bufB, nullptr, row_ptr, edges, nullptr, out);
    } else {
        // fallback: atomic scatter path
        float* x = (float*)d_ws;
        float* y = x + embN;
        const size_t emb_bytes = embN * sizeof(float);
        {
            int total = NNODE * EMB / 4;
            init_kernel<<<(total + 255) / 256, 256, 0, stream>>>(user_emb, item_emb, x, out);
        }
        for (int layer = 0; layer < 3; ++layer) {
            hipMemsetAsync(y, 0, emb_bytes, stream);
            long long threads = (long long)nnz * 16;
            scatter_kernel<<<(int)((threads + 255) / 256), 256, 0, stream>>>(x, y, vals, rows, cols, nnz);
            int total = NNODE * EMB / 4;
            accum_kernel<<<(total + 255) / 256, 256, 0, stream>>>(out, y, layer < 2 ? 1.0f : (1.0f / 3.0f));
            float* t = x; x = y; y = t;
        }
    }
}

// Round 8
// 294.545 us; speedup vs baseline: 1.1066x; 1.0064x over previous
//
#include <hip/hip_runtime.h>

#define USER_NUM 80000
#define ITEM_NUM 40000
#define NNODE (USER_NUM + ITEM_NUM)
#define EMB 64
#define NB 469            // ceil(NNODE / 256) buckets of 256 rows
#define P1_CHUNK 4096

// ===========================================================================
// Build step 1: coarse histogram of row>>8 (LDS-aggregated, int4 loads)
// ===========================================================================
__global__ void bucket_hist_kernel(const int* __restrict__ rows, int* __restrict__ bcounts, int nnz) {
    __shared__ int h[NB];
    for (int i = threadIdx.x; i < NB; i += blockDim.x) h[i] = 0;
    __syncthreads();
    int nq = nnz >> 2;
    int stride = gridDim.x * blockDim.x;
    for (int i = blockIdx.x * blockDim.x + threadIdx.x; i < nq; i += stride) {
        int4 r = ((const int4*)rows)[i];
        atomicAdd(&h[r.x >> 8], 1);
        atomicAdd(&h[r.y >> 8], 1);
        atomicAdd(&h[r.z >> 8], 1);
        atomicAdd(&h[r.w >> 8], 1);
    }
    // tail
    if (blockIdx.x == 0) {
        for (int i = (nq << 2) + threadIdx.x; i < nnz; i += blockDim.x)
            atomicAdd(&h[rows[i] >> 8], 1);
    }
    __syncthreads();
    for (int i = threadIdx.x; i < NB; i += blockDim.x)
        if (h[i]) atomicAdd(&bcounts[i], h[i]);
}

// ===========================================================================
// Build step 2: exclusive scan of 469 bucket counts (single block)
// ===========================================================================
__global__ void bucket_scan_kernel(const int* __restrict__ bcounts, int* __restrict__ bucket_off,
                                   int* __restrict__ bcursor, int* __restrict__ row_ptr, int nnz) {
    __shared__ int lds[512];
    int t = threadIdx.x;
    int v = (t < NB) ? bcounts[t] : 0;
    lds[t] = v;
    __syncthreads();
    for (int off = 1; off < 512; off <<= 1) {
        int add = (t >= off) ? lds[t - off] : 0;
        __syncthreads();
        lds[t] += add;
        __syncthreads();
    }
    if (t < NB) {
        int ex = lds[t] - v;
        bucket_off[t] = ex;
        bcursor[t]    = ex;
    }
    if (t == 0) { bucket_off[NB] = nnz; row_ptr[NNODE] = nnz; }
}

// ===========================================================================
// Build step 3: bin edges into buckets (one global atomic per block,bucket;
// sequential line-friendly writes). tmp packs {col | row_local<<17, val_bits}.
// ===========================================================================
__global__ void phase1_kernel(const int* __restrict__ rows, const int* __restrict__ cols,
                              const float* __restrict__ vals, int* __restrict__ bcursor,
                              int2* __restrict__ tmp, int nnz) {
    __shared__ int h[NB];
    __shared__ int base[NB];
    int t = threadIdx.x;
    for (int i = t; i < NB; i += 256) h[i] = 0;
    __syncthreads();
    int lo = blockIdx.x * P1_CHUNK;
    int hi = lo + P1_CHUNK; if (hi > nnz) hi = nnz;
    for (int i = lo + t; i < hi; i += 256)
        atomicAdd(&h[rows[i] >> 8], 1);
    __syncthreads();
    for (int i = t; i < NB; i += 256) {
        int c = h[i];
        base[i] = c ? atomicAdd(&bcursor[i], c) : 0;
        h[i] = 0;
    }
    __syncthreads();
    for (int i = lo + t; i < hi; i += 256) {
        int r = rows[i];
        int b = r >> 8;
        int loc = atomicAdd(&h[b], 1);
        tmp[base[b] + loc] = make_int2(cols[i] | ((r & 255) << 17), __float_as_int(vals[i]));
    }
}

// ===========================================================================
// Build step 4: one block per bucket, exact per-row counts + scan -> row_ptr;
// LDS cursors place edges into final CSR.
// ===========================================================================
__global__ void phase2_kernel(const int2* __restrict__ tmp, const int* __restrict__ bucket_off,
                              int* __restrict__ row_ptr, int2* __restrict__ edges) {
    __shared__ int hist[256];
    __shared__ int scan[256];
    __shared__ int cur[256];
    int b = blockIdx.x;
    int t = threadIdx.x;
    int row0  = b << 8;
    int nrows = NNODE - row0; if (nrows > 256) nrows = 256;
    int start = bucket_off[b];
    int end   = bucket_off[b + 1];
    hist[t] = 0;
    __syncthreads();
    for (int j = start + t; j < end; j += 256)
        atomicAdd(&hist[tmp[j].x >> 17], 1);
    __syncthreads();
    int v = hist[t];
    scan[t] = v;
    __syncthreads();
    for (int off = 1; off < 256; off <<= 1) {
        int add = (t >= off) ? scan[t - off] : 0;
        __syncthreads();
        scan[t] += add;
        __syncthreads();
    }
    int ex = scan[t] - v + start;   // exclusive prefix + bucket base
    if (t < nrows) row_ptr[row0 + t] = ex;
    cur[t] = ex;
    __syncthreads();
    for (int j = start + t; j < end; j += 256) {
        int2 e  = tmp[j];
        int rl  = e.x >> 17;
        int pos = atomicAdd(&cur[rl], 1);
        edges[pos] = make_int2(e.x & 0x1FFFF, e.y);
    }
}

// ===========================================================================
// CSR SpMM: wave owns 4 rows; lane group g (16 lanes) owns row r0+g; lane
// c=(lane&15) holds dims [4c,4c+4). Per-lane int2 edge loads (no readlane),
// dwordx4 gathers (1 KB/instr = 4 edges). Pads: exec-masked edge load ->
// int2(0,0) -> zero val, gather hits hot row 0. Unroll 4 for MLP. Edge loads
// nontemporal (streamed once) to keep L2 capacity for x rows.
// ===========================================================================
template <int LAYER>
__launch_bounds__(256)
__global__ void spmm_kernel(const float* __restrict__ xu, const float* __restrict__ xi,
                            const int* __restrict__ row_ptr, const int2* __restrict__ edges,
                            float* __restrict__ y, float* __restrict__ out) {
    int wave = (blockIdx.x * blockDim.x + threadIdx.x) >> 6;
    int lane = threadIdx.x & 63;
    int r0 = wave << 2;                    // 4 rows per wave; NNODE % 4 == 0
    if (r0 >= NNODE) return;
    int g = lane >> 4;                     // which of the 4 rows
    int c = lane & 15;                     // which float4 chunk of the row

    int rp = 0;
    if (lane < 5) rp = row_ptr[r0 + lane];
    int p0 = __builtin_amdgcn_readlane(rp, 0);
    int p1 = __builtin_amdgcn_readlane(rp, 1);
    int p2 = __builtin_amdgcn_readlane(rp, 2);
    int p3 = __builtin_amdgcn_readlane(rp, 3);
    int p4 = __builtin_amdgcn_readlane(rp, 4);

    int sg = (g == 0) ? p0 : (g == 1) ? p1 : (g == 2) ? p2 : p3;   // row start
    int eg = (g == 0) ? p1 : (g == 1) ? p2 : (g == 2) ? p3 : p4;   // row end
    int maxd = max(max(p1 - p0, p2 - p1), max(p3 - p2, p4 - p3));  // wave loop bound

    float4 acc = make_float4(0.f, 0.f, 0.f, 0.f);

    for (int j = 0; j < maxd; j += 4) {
        long long ev[4];
        #pragma unroll
        for (int u = 0; u < 4; ++u) {
            int i = sg + j + u;
            ev[u] = (i < eg) ? __builtin_nontemporal_load((const long long*)(edges + i)) : 0LL;
        }
        #pragma unroll
        for (int u = 0; u < 4; ++u) {
            int   col = (int)(unsigned)ev[u];
            float v   = __int_as_float((int)(ev[u] >> 32));
            const float* q;
            if (LAYER == 1)
                q = (col < USER_NUM) ? xu + (size_t)col * EMB : xi + (size_t)(col - USER_NUM) * EMB;
            else
                q = xu + (size_t)col * EMB;
            float4 gv = ((const float4*)q)[c];
            acc.x += v * gv.x; acc.y += v * gv.y; acc.z += v * gv.z; acc.w += v * gv.w;
        }
    }

    size_t o = (size_t)(r0 + g) * EMB + (size_t)c * 4;
    float4* yp = (float4*)(y + o);
    float4* op = (float4*)(out + o);
    if (LAYER == 1) {
        *yp = acc;
        *op = acc;
    } else if (LAYER == 2) {
        *yp = acc;
        float4 t = *op;
        t.x += acc.x; t.y += acc.y; t.z += acc.z; t.w += acc.w;
        *op = t;
    } else {
        const float s = 1.0f / 3.0f;
        float4 t = *op;
        t.x = (t.x + acc.x) * s; t.y = (t.y + acc.y) * s;
        t.z = (t.z + acc.z) * s; t.w = (t.w + acc.w) * s;
        *op = t;
    }
}

// ===========================================================================
// Fallback (atomic path) in case ws_size is too small for CSR arrays
// ===========================================================================
__global__ void init_kernel(const float* __restrict__ user_emb, const float* __restrict__ item_emb,
                            float* __restrict__ x, float* __restrict__ out) {
    int idx = blockIdx.x * blockDim.x + threadIdx.x;
    const int total = NNODE * EMB / 4;
    if (idx >= total) return;
    const int user_total = USER_NUM * EMB / 4;
    float4 v = (idx < user_total) ? ((const float4*)user_emb)[idx]
                                  : ((const float4*)item_emb)[idx - user_total];
    ((float4*)x)[idx]   = v;
    ((float4*)out)[idx] = make_float4(0.f, 0.f, 0.f, 0.f);
}

__global__ void scatter_kernel(const float* __restrict__ x, float* __restrict__ y,
                               const float* __restrict__ vals, const int* __restrict__ rows,
                               const int* __restrict__ cols, int nnz) {
    int tid = blockIdx.x * blockDim.x + threadIdx.x;
    int e = tid >> 4;
    if (e >= nnz) return;
    int c = tid & 15;
    int r = rows[e], col = cols[e];
    float v = vals[e];
    float4 xv = ((const float4*)(x + (size_t)col * EMB))[c];
    float* dst = y + (size_t)r * EMB + (size_t)c * 4;
    atomicAdd(dst + 0, xv.x * v);
    atomicAdd(dst + 1, xv.y * v);
    atomicAdd(dst + 2, xv.z * v);
    atomicAdd(dst + 3, xv.w * v);
}

__global__ void accum_kernel(float* __restrict__ out, const float* __restrict__ y, float scale) {
    int idx = blockIdx.x * blockDim.x + threadIdx.x;
    const int total = NNODE * EMB / 4;
    if (idx >= total) return;
    float4 o = ((float4*)out)[idx];
    float4 a = ((const float4*)y)[idx];
    o.x = (o.x + a.x) * scale; o.y = (o.y + a.y) * scale;
    o.z = (o.z + a.z) * scale; o.w = (o.w + a.w) * scale;
    ((float4*)out)[idx] = o;
}

extern "C" void kernel_launch(void* const* d_in, const int* in_sizes, int n_in,
                              void* d_out, int out_size, void* d_ws, size_t ws_size,
                              hipStream_t stream) {
    const float* user_emb = (const float*)d_in[0];
    const float* item_emb = (const float*)d_in[1];
    const float* vals     = (const float*)d_in[2];
    const int*   rows     = (const int*)d_in[3];
    const int*   cols     = (const int*)d_in[4];
    const int    nnz      = in_sizes[2];

    float* out = (float*)d_out;

    const size_t embN   = (size_t)NNODE * EMB;        // 7,680,000 floats
    const size_t rp_pad = 120064;                     // NNODE+1 rounded up (8B-align after)

    // Persistent ws layout:
    //   bufA: embN floats | bufB: embN floats | row_ptr: rp_pad ints | edges: nnz int2
    // Build-time aliases (dead before their host buffer is written):
    //   tmp (nnz int2) -> front of bufA; bcounts/bucket_off/bcursor -> front of bufB
    size_t need = (2 * embN + rp_pad) * 4 + (size_t)nnz * 8;

    if (ws_size >= need) {
        float* bufA    = (float*)d_ws;
        float* bufB    = bufA + embN;
        int*   row_ptr = (int*)(bufB + embN);
        int2*  edges   = (int2*)(row_ptr + rp_pad);

        int2* tmp        = (int2*)bufA;
        int*  bcounts    = (int*)bufB;
        int*  bucket_off = bcounts + 512;       // NB+1 used
        int*  bcursor    = bucket_off + 512;

        // --- build CSR (two-pass LDS-binned counting sort) ---
        hipMemsetAsync(bcounts, 0, NB * sizeof(int), stream);
        bucket_hist_kernel<<<256, 256, 0, stream>>>(rows, bcounts, nnz);
        bucket_scan_kernel<<<1, 512, 0, stream>>>(bcounts, bucket_off, bcursor, row_ptr, nnz);
        phase1_kernel<<<(nnz + P1_CHUNK - 1) / P1_CHUNK, 256, 0, stream>>>(rows, cols, vals, bcursor, tmp, nnz);
        phase2_kernel<<<NB, 256, 0, stream>>>(tmp, bucket_off, row_ptr, edges);

        // --- 3 propagation layers, accumulation fused into epilogues ---
        const int nwaves = NNODE / 4;                      // 4 rows per wave
        const int blocks = (nwaves * 64 + 255) / 256;      // 4 waves per block
        spmm_kernel<1><<<blocks, 256, 0, stream>>>(user_emb, item_emb, row_ptr, edges, bufA, out);
        spmm_kernel<2><<<blocks, 256, 0, stream>>>(bufA, nullptr, row_ptr, edges, bufB, out);
        spmm_kernel<3><<<blocks, 256, 0, stream>>>(bufB, nullptr, row_ptr, edges, nullptr, out);
    } else {
        // fallback: atomic scatter path
        float* x = (float*)d_ws;
        float* y = x + embN;
        const size_t emb_bytes = embN * sizeof(float);
        {
            int total = NNODE * EMB / 4;
            init_kernel<<<(total + 255) / 256, 256, 0, stream>>>(user_emb, item_emb, x, out);
        }
        for (int layer = 0; layer < 3; ++layer) {
            hipMemsetAsync(y, 0, emb_bytes, stream);
            long long threads = (long long)nnz * 16;
            scatter_kernel<<<(int)((threads + 255) / 256), 256, 0, stream>>>(x, y, vals, rows, cols, nnz);
            int total = NNODE * EMB / 4;
            accum_kernel<<<(total + 255) / 256, 256, 0, stream>>>(out, y, layer < 2 ? 1.0f : (1.0f / 3.0f));
            float* t = x; x = y; y = t;
        }
    }
}

// Round 9
// 290.784 us; speedup vs baseline: 1.1209x; 1.0129x over previous
//
#include <hip/hip_runtime.h>

#define USER_NUM 80000
#define ITEM_NUM 40000
#define NNODE (USER_NUM + ITEM_NUM)
#define EMB 64
#define NB 469            // ceil(NNODE / 256) buckets of 256 rows
#define P1_CHUNK 4096

// ===========================================================================
// Build step 1: coarse histogram of row>>8 (LDS-aggregated, int4 loads)
// ===========================================================================
__global__ void bucket_hist_kernel(const int* __restrict__ rows, int* __restrict__ bcounts, int nnz) {
    __shared__ int h[NB];
    for (int i = threadIdx.x; i < NB; i += blockDim.x) h[i] = 0;
    __syncthreads();
    int nq = nnz >> 2;
    int stride = gridDim.x * blockDim.x;
    for (int i = blockIdx.x * blockDim.x + threadIdx.x; i < nq; i += stride) {
        int4 r = ((const int4*)rows)[i];
        atomicAdd(&h[r.x >> 8], 1);
        atomicAdd(&h[r.y >> 8], 1);
        atomicAdd(&h[r.z >> 8], 1);
        atomicAdd(&h[r.w >> 8], 1);
    }
    // tail
    if (blockIdx.x == 0) {
        for (int i = (nq << 2) + threadIdx.x; i < nnz; i += blockDim.x)
            atomicAdd(&h[rows[i] >> 8], 1);
    }
    __syncthreads();
    for (int i = threadIdx.x; i < NB; i += blockDim.x)
        if (h[i]) atomicAdd(&bcounts[i], h[i]);
}

// ===========================================================================
// Build step 2: exclusive scan of 469 bucket counts (single block)
// ===========================================================================
__global__ void bucket_scan_kernel(const int* __restrict__ bcounts, int* __restrict__ bucket_off,
                                   int* __restrict__ bcursor, int* __restrict__ row_ptr, int nnz) {
    __shared__ int lds[512];
    int t = threadIdx.x;
    int v = (t < NB) ? bcounts[t] : 0;
    lds[t] = v;
    __syncthreads();
    for (int off = 1; off < 512; off <<= 1) {
        int add = (t >= off) ? lds[t - off] : 0;
        __syncthreads();
        lds[t] += add;
        __syncthreads();
    }
    if (t < NB) {
        int ex = lds[t] - v;
        bucket_off[t] = ex;
        bcursor[t]    = ex;
    }
    if (t == 0) { bucket_off[NB] = nnz; row_ptr[NNODE] = nnz; }
}

// ===========================================================================
// Build step 3: bin edges into buckets (one global atomic per block,bucket;
// sequential line-friendly writes). tmp packs {col | row_local<<17, val_bits}.
// ===========================================================================
__global__ void phase1_kernel(const int* __restrict__ rows, const int* __restrict__ cols,
                              const float* __restrict__ vals, int* __restrict__ bcursor,
                              int2* __restrict__ tmp, int nnz) {
    __shared__ int h[NB];
    __shared__ int base[NB];
    int t = threadIdx.x;
    for (int i = t; i < NB; i += 256) h[i] = 0;
    __syncthreads();
    int lo = blockIdx.x * P1_CHUNK;
    int hi = lo + P1_CHUNK; if (hi > nnz) hi = nnz;
    for (int i = lo + t; i < hi; i += 256)
        atomicAdd(&h[rows[i] >> 8], 1);
    __syncthreads();
    for (int i = t; i < NB; i += 256) {
        int c = h[i];
        base[i] = c ? atomicAdd(&bcursor[i], c) : 0;
        h[i] = 0;
    }
    __syncthreads();
    for (int i = lo + t; i < hi; i += 256) {
        int r = rows[i];
        int b = r >> 8;
        int loc = atomicAdd(&h[b], 1);
        tmp[base[b] + loc] = make_int2(cols[i] | ((r & 255) << 17), __float_as_int(vals[i]));
    }
}

// ===========================================================================
// Build step 4: one block per bucket, exact per-row counts + scan -> row_ptr;
// LDS cursors place edges into final CSR.
// ===========================================================================
__global__ void phase2_kernel(const int2* __restrict__ tmp, const int* __restrict__ bucket_off,
                              int* __restrict__ row_ptr, int2* __restrict__ edges) {
    __shared__ int hist[256];
    __shared__ int scan[256];
    __shared__ int cur[256];
    int b = blockIdx.x;
    int t = threadIdx.x;
    int row0  = b << 8;
    int nrows = NNODE - row0; if (nrows > 256) nrows = 256;
    int start = bucket_off[b];
    int end   = bucket_off[b + 1];
    hist[t] = 0;
    __syncthreads();
    for (int j = start + t; j < end; j += 256)
        atomicAdd(&hist[tmp[j].x >> 17], 1);
    __syncthreads();
    int v = hist[t];
    scan[t] = v;
    __syncthreads();
    for (int off = 1; off < 256; off <<= 1) {
        int add = (t >= off) ? scan[t - off] : 0;
        __syncthreads();
        scan[t] += add;
        __syncthreads();
    }
    int ex = scan[t] - v + start;   // exclusive prefix + bucket base
    if (t < nrows) row_ptr[row0 + t] = ex;
    cur[t] = ex;
    __syncthreads();
    for (int j = start + t; j < end; j += 256) {
        int2 e  = tmp[j];
        int rl  = e.x >> 17;
        int pos = atomicAdd(&cur[rl], 1);
        edges[pos] = make_int2(e.x & 0x1FFFF, e.y);
    }
}

// ===========================================================================
// CSR SpMM: wave owns 4 rows; lane group g (16 lanes) owns row r0+g; lane
// c=(lane&15) holds dims [4c,4c+4). Per-lane int2 edge loads (no readlane),
// dwordx4 gathers (1 KB/instr = 4 edges). Pads: exec-masked edge load ->
// int2(0,0) -> zero val, gather hits hot row-0 line. Unroll 8 for MLP.
// Edge loads CACHED (R8's nontemporal lost cross-wave line reuse: +11 MB L2
// fills — reverted).
// ===========================================================================
template <int LAYER>
__launch_bounds__(256)
__global__ void spmm_kernel(const float* __restrict__ xu, const float* __restrict__ xi,
                            const int* __restrict__ row_ptr, const int2* __restrict__ edges,
                            float* __restrict__ y, float* __restrict__ out) {
    int wave = (blockIdx.x * blockDim.x + threadIdx.x) >> 6;
    int lane = threadIdx.x & 63;
    int r0 = wave << 2;                    // 4 rows per wave; NNODE % 4 == 0
    if (r0 >= NNODE) return;
    int g = lane >> 4;                     // which of the 4 rows
    int c = lane & 15;                     // which float4 chunk of the row

    int rp = 0;
    if (lane < 5) rp = row_ptr[r0 + lane];
    int p0 = __builtin_amdgcn_readlane(rp, 0);
    int p1 = __builtin_amdgcn_readlane(rp, 1);
    int p2 = __builtin_amdgcn_readlane(rp, 2);
    int p3 = __builtin_amdgcn_readlane(rp, 3);
    int p4 = __builtin_amdgcn_readlane(rp, 4);

    int sg = (g == 0) ? p0 : (g == 1) ? p1 : (g == 2) ? p2 : p3;   // row start
    int eg = (g == 0) ? p1 : (g == 1) ? p2 : (g == 2) ? p3 : p4;   // row end
    int maxd = max(max(p1 - p0, p2 - p1), max(p3 - p2, p4 - p3));  // wave loop bound

    float4 acc = make_float4(0.f, 0.f, 0.f, 0.f);

    for (int j = 0; j < maxd; j += 8) {
        long long ev[8];
        #pragma unroll
        for (int u = 0; u < 8; ++u) {
            int i = sg + j + u;
            ev[u] = (i < eg) ? *(const long long*)(edges + i) : 0LL;
        }
        #pragma unroll
        for (int u = 0; u < 8; ++u) {
            int   col = (int)(unsigned)ev[u];
            float v   = __int_as_float((int)(ev[u] >> 32));
            const float* q;
            if (LAYER == 1)
                q = (col < USER_NUM) ? xu + (size_t)col * EMB : xi + (size_t)(col - USER_NUM) * EMB;
            else
                q = xu + (size_t)col * EMB;
            float4 gv = ((const float4*)q)[c];
            acc.x += v * gv.x; acc.y += v * gv.y; acc.z += v * gv.z; acc.w += v * gv.w;
        }
    }

    size_t o = (size_t)(r0 + g) * EMB + (size_t)c * 4;
    float4* yp = (float4*)(y + o);
    float4* op = (float4*)(out + o);
    if (LAYER == 1) {
        *yp = acc;
        *op = acc;
    } else if (LAYER == 2) {
        *yp = acc;
        float4 t = *op;
        t.x += acc.x; t.y += acc.y; t.z += acc.z; t.w += acc.w;
        *op = t;
    } else {
        const float s = 1.0f / 3.0f;
        float4 t = *op;
        t.x = (t.x + acc.x) * s; t.y = (t.y + acc.y) * s;
        t.z = (t.z + acc.z) * s; t.w = (t.w + acc.w) * s;
        *op = t;
    }
}

// ===========================================================================
// Fallback (atomic path) in case ws_size is too small for CSR arrays
// ===========================================================================
__global__ void init_kernel(const float* __restrict__ user_emb, const float* __restrict__ item_emb,
                            float* __restrict__ x, float* __restrict__ out) {
    int idx = blockIdx.x * blockDim.x + threadIdx.x;
    const int total = NNODE * EMB / 4;
    if (idx >= total) return;
    const int user_total = USER_NUM * EMB / 4;
    float4 v = (idx < user_total) ? ((const float4*)user_emb)[idx]
                                  : ((const float4*)item_emb)[idx - user_total];
    ((float4*)x)[idx]   = v;
    ((float4*)out)[idx] = make_float4(0.f, 0.f, 0.f, 0.f);
}

__global__ void scatter_kernel(const float* __restrict__ x, float* __restrict__ y,
                               const float* __restrict__ vals, const int* __restrict__ rows,
                               const int* __restrict__ cols, int nnz) {
    int tid = blockIdx.x * blockDim.x + threadIdx.x;
    int e = tid >> 4;
    if (e >= nnz) return;
    int c = tid & 15;
    int r = rows[e], col = cols[e];
    float v = vals[e];
    float4 xv = ((const float4*)(x + (size_t)col * EMB))[c];
    float* dst = y + (size_t)r * EMB + (size_t)c * 4;
    atomicAdd(dst + 0, xv.x * v);
    atomicAdd(dst + 1, xv.y * v);
    atomicAdd(dst + 2, xv.z * v);
    atomicAdd(dst + 3, xv.w * v);
}

__global__ void accum_kernel(float* __restrict__ out, const float* __restrict__ y, float scale) {
    int idx = blockIdx.x * blockDim.x + threadIdx.x;
    const int total = NNODE * EMB / 4;
    if (idx >= total) return;
    float4 o = ((float4*)out)[idx];
    float4 a = ((const float4*)y)[idx];
    o.x = (o.x + a.x) * scale; o.y = (o.y + a.y) * scale;
    o.z = (o.z + a.z) * scale; o.w = (o.w + a.w) * scale;
    ((float4*)out)[idx] = o;
}

extern "C" void kernel_launch(void* const* d_in, const int* in_sizes, int n_in,
                              void* d_out, int out_size, void* d_ws, size_t ws_size,
                              hipStream_t stream) {
    const float* user_emb = (const float*)d_in[0];
    const float* item_emb = (const float*)d_in[1];
    const float* vals     = (const float*)d_in[2];
    const int*   rows     = (const int*)d_in[3];
    const int*   cols     = (const int*)d_in[4];
    const int    nnz      = in_sizes[2];

    float* out = (float*)d_out;

    const size_t embN   = (size_t)NNODE * EMB;        // 7,680,000 floats
    const size_t rp_pad = 120064;                     // NNODE+1 rounded up (8B-align after)

    // Persistent ws layout:
    //   bufA: embN floats | bufB: embN floats | row_ptr: rp_pad ints | edges: nnz int2
    // Build-time aliases (dead before their host buffer is written):
    //   tmp (nnz int2) -> front of bufA; bcounts/bucket_off/bcursor -> front of bufB
    size_t need = (2 * embN + rp_pad) * 4 + (size_t)nnz * 8;

    if (ws_size >= need) {
        float* bufA    = (float*)d_ws;
        float* bufB    = bufA + embN;
        int*   row_ptr = (int*)(bufB + embN);
        int2*  edges   = (int2*)(row_ptr + rp_pad);

        int2* tmp        = (int2*)bufA;
        int*  bcounts    = (int*)bufB;
        int*  bucket_off = bcounts + 512;       // NB+1 used
        int*  bcursor    = bucket_off + 512;

        // --- build CSR (two-pass LDS-binned counting sort) ---
        hipMemsetAsync(bcounts, 0, NB * sizeof(int), stream);
        bucket_hist_kernel<<<256, 256, 0, stream>>>(rows, bcounts, nnz);
        bucket_scan_kernel<<<1, 512, 0, stream>>>(bcounts, bucket_off, bcursor, row_ptr, nnz);
        phase1_kernel<<<(nnz + P1_CHUNK - 1) / P1_CHUNK, 256, 0, stream>>>(rows, cols, vals, bcursor, tmp, nnz);
        phase2_kernel<<<NB, 256, 0, stream>>>(tmp, bucket_off, row_ptr, edges);

        // --- 3 propagation layers, accumulation fused into epilogues ---
        const int nwaves = NNODE / 4;                      // 4 rows per wave
        const int blocks = (nwaves * 64 + 255) / 256;      // 4 waves per block
        spmm_kernel<1><<<blocks, 256, 0, stream>>>(user_emb, item_emb, row_ptr, edges, bufA, out);
        spmm_kernel<2><<<blocks, 256, 0, stream>>>(bufA, nullptr, row_ptr, edges, bufB, out);
        spmm_kernel<3><<<blocks, 256, 0, stream>>>(bufB, nullptr, row_ptr, edges, nullptr, out);
    } else {
        // fallback: atomic scatter path
        float* x = (float*)d_ws;
        float* y = x + embN;
        const size_t emb_bytes = embN * sizeof(float);
        {
            int total = NNODE * EMB / 4;
            init_kernel<<<(total + 255) / 256, 256, 0, stream>>>(user_emb, item_emb, x, out);
        }
        for (int layer = 0; layer < 3; ++layer) {
            hipMemsetAsync(y, 0, emb_bytes, stream);
            long long threads = (long long)nnz * 16;
            scatter_kernel<<<(int)((threads + 255) / 256), 256, 0, stream>>>(x, y, vals, rows, cols, nnz);
            int total = NNODE * EMB / 4;
            accum_kernel<<<(total + 255) / 256, 256, 0, stream>>>(out, y, layer < 2 ? 1.0f : (1.0f / 3.0f));
            float* t = x; x = y; y = t;
        }
    }
}

// Round 10
// 277.505 us; speedup vs baseline: 1.1746x; 1.0479x over previous
//
#include <hip/hip_runtime.h>

#define USER_NUM 80000
#define ITEM_NUM 40000
#define NNODE (USER_NUM + ITEM_NUM)
#define EMB 64
#define NB 469            // ceil(NNODE / 256) buckets of 256 rows
#define P1_CHUNK 4096

// ===========================================================================
// Build step 1: coarse histogram of row>>8 (LDS-aggregated, int4 loads)
// ===========================================================================
__global__ void bucket_hist_kernel(const int* __restrict__ rows, int* __restrict__ bcounts, int nnz) {
    __shared__ int h[NB];
    for (int i = threadIdx.x; i < NB; i += blockDim.x) h[i] = 0;
    __syncthreads();
    int nq = nnz >> 2;
    int stride = gridDim.x * blockDim.x;
    for (int i = blockIdx.x * blockDim.x + threadIdx.x; i < nq; i += stride) {
        int4 r = ((const int4*)rows)[i];
        atomicAdd(&h[r.x >> 8], 1);
        atomicAdd(&h[r.y >> 8], 1);
        atomicAdd(&h[r.z >> 8], 1);
        atomicAdd(&h[r.w >> 8], 1);
    }
    if (blockIdx.x == 0) {
        for (int i = (nq << 2) + threadIdx.x; i < nnz; i += blockDim.x)
            atomicAdd(&h[rows[i] >> 8], 1);
    }
    __syncthreads();
    for (int i = threadIdx.x; i < NB; i += blockDim.x)
        if (h[i]) atomicAdd(&bcounts[i], h[i]);
}

// ===========================================================================
// Build step 2: exclusive scan of 469 bucket counts (single block)
// ===========================================================================
__global__ void bucket_scan_kernel(const int* __restrict__ bcounts, int* __restrict__ bucket_off,
                                   int* __restrict__ bcursor, int* __restrict__ row_ptr, int nnz) {
    __shared__ int lds[512];
    int t = threadIdx.x;
    int v = (t < NB) ? bcounts[t] : 0;
    lds[t] = v;
    __syncthreads();
    for (int off = 1; off < 512; off <<= 1) {
        int add = (t >= off) ? lds[t - off] : 0;
        __syncthreads();
        lds[t] += add;
        __syncthreads();
    }
    if (t < NB) {
        int ex = lds[t] - v;
        bucket_off[t] = ex;
        bcursor[t]    = ex;
    }
    if (t == 0) { bucket_off[NB] = nnz; row_ptr[NNODE] = nnz; }
}

// ===========================================================================
// Build step 3: bin edges into buckets (one global atomic per block,bucket;
// sequential line-friendly writes). Vectorized int4/float4 input reads.
// tmp packs {col | row_local<<17, val_bits}.
// ===========================================================================
__global__ void phase1_kernel(const int* __restrict__ rows, const int* __restrict__ cols,
                              const float* __restrict__ vals, int* __restrict__ bcursor,
                              int2* __restrict__ tmp, int nnz) {
    __shared__ int h[NB];
    __shared__ int base[NB];
    int t = threadIdx.x;
    for (int i = t; i < NB; i += 256) h[i] = 0;
    __syncthreads();
    int lo = blockIdx.x * P1_CHUNK;
    int hi = lo + P1_CHUNK; if (hi > nnz) hi = nnz;
    int n4 = (hi - lo) >> 2;                    // lo is 16B-aligned (P1_CHUNK%4==0)
    const int4*   rows4 = (const int4*)(rows + lo);
    const int4*   cols4 = (const int4*)(cols + lo);
    const float4* vals4 = (const float4*)(vals + lo);

    for (int i = t; i < n4; i += 256) {
        int4 r = rows4[i];
        atomicAdd(&h[r.x >> 8], 1);
        atomicAdd(&h[r.y >> 8], 1);
        atomicAdd(&h[r.z >> 8], 1);
        atomicAdd(&h[r.w >> 8], 1);
    }
    for (int i = lo + (n4 << 2) + t; i < hi; i += 256)
        atomicAdd(&h[rows[i] >> 8], 1);
    __syncthreads();
    for (int i = t; i < NB; i += 256) {
        int c = h[i];
        base[i] = c ? atomicAdd(&bcursor[i], c) : 0;
        h[i] = 0;
    }
    __syncthreads();
    for (int i = t; i < n4; i += 256) {
        int4 r = rows4[i];
        int4 c = cols4[i];
        float4 v = vals4[i];
        {
            int b = r.x >> 8; int loc = atomicAdd(&h[b], 1);
            tmp[base[b] + loc] = make_int2(c.x | ((r.x & 255) << 17), __float_as_int(v.x));
        }
        {
            int b = r.y >> 8; int loc = atomicAdd(&h[b], 1);
            tmp[base[b] + loc] = make_int2(c.y | ((r.y & 255) << 17), __float_as_int(v.y));
        }
        {
            int b = r.z >> 8; int loc = atomicAdd(&h[b], 1);
            tmp[base[b] + loc] = make_int2(c.z | ((r.z & 255) << 17), __float_as_int(v.z));
        }
        {
            int b = r.w >> 8; int loc = atomicAdd(&h[b], 1);
            tmp[base[b] + loc] = make_int2(c.w | ((r.w & 255) << 17), __float_as_int(v.w));
        }
    }
    for (int i = lo + (n4 << 2) + t; i < hi; i += 256) {
        int r = rows[i];
        int b = r >> 8;
        int loc = atomicAdd(&h[b], 1);
        tmp[base[b] + loc] = make_int2(cols[i] | ((r & 255) << 17), __float_as_int(vals[i]));
    }
}

// ===========================================================================
// Build step 4: one block per bucket, exact per-row counts + scan -> row_ptr;
// LDS cursors place edges into final CSR.
// ===========================================================================
__global__ void phase2_kernel(const int2* __restrict__ tmp, const int* __restrict__ bucket_off,
                              int* __restrict__ row_ptr, int2* __restrict__ edges) {
    __shared__ int hist[256];
    __shared__ int scan[256];
    __shared__ int cur[256];
    int b = blockIdx.x;
    int t = threadIdx.x;
    int row0  = b << 8;
    int nrows = NNODE - row0; if (nrows > 256) nrows = 256;
    int start = bucket_off[b];
    int end   = bucket_off[b + 1];
    hist[t] = 0;
    __syncthreads();
    for (int j = start + t; j < end; j += 256)
        atomicAdd(&hist[tmp[j].x >> 17], 1);
    __syncthreads();
    int v = hist[t];
    scan[t] = v;
    __syncthreads();
    for (int off = 1; off < 256; off <<= 1) {
        int add = (t >= off) ? scan[t - off] : 0;
        __syncthreads();
        scan[t] += add;
        __syncthreads();
    }
    int ex = scan[t] - v + start;   // exclusive prefix + bucket base
    if (t < nrows) row_ptr[row0 + t] = ex;
    cur[t] = ex;
    __syncthreads();
    for (int j = start + t; j < end; j += 256) {
        int2 e  = tmp[j];
        int rl  = e.x >> 17;
        int pos = atomicAdd(&cur[rl], 1);
        edges[pos] = make_int2(e.x & 0x1FFFF, e.y);
    }
}

// ===========================================================================
// CSR SpMM: wave owns 4 rows; lane group g (16 lanes) owns row r0+g; lane
// c=(lane&15) holds dims [4c,4c+4). Per-lane int2 edge loads (no readlane),
// dwordx4 gathers (1 KB/instr = 4 edges). Pads exec-masked -> int2(0,0).
// SOFTWARE PIPELINE: prefetch next edge octet before this octet's gathers,
// overlapping edge-load latency with gather latency.
// ===========================================================================
__device__ __forceinline__ void load8(long long ev[8], const int2* __restrict__ edges,
                                      int sg, int eg, int j) {
    #pragma unroll
    for (int u = 0; u < 8; ++u) {
        int i = sg + j + u;
        ev[u] = (i < eg) ? *(const long long*)(edges + i) : 0LL;
    }
}

template <int LAYER>
__launch_bounds__(256)
__global__ void spmm_kernel(const float* __restrict__ xu, const float* __restrict__ xi,
                            const int* __restrict__ row_ptr, const int2* __restrict__ edges,
                            float* __restrict__ y, float* __restrict__ out) {
    int wave = (blockIdx.x * blockDim.x + threadIdx.x) >> 6;
    int lane = threadIdx.x & 63;
    int r0 = wave << 2;                    // 4 rows per wave; NNODE % 4 == 0
    if (r0 >= NNODE) return;
    int g = lane >> 4;                     // which of the 4 rows
    int c = lane & 15;                     // which float4 chunk of the row

    int rp = 0;
    if (lane < 5) rp = row_ptr[r0 + lane];
    int p0 = __builtin_amdgcn_readlane(rp, 0);
    int p1 = __builtin_amdgcn_readlane(rp, 1);
    int p2 = __builtin_amdgcn_readlane(rp, 2);
    int p3 = __builtin_amdgcn_readlane(rp, 3);
    int p4 = __builtin_amdgcn_readlane(rp, 4);

    int sg = (g == 0) ? p0 : (g == 1) ? p1 : (g == 2) ? p2 : p3;   // row start
    int eg = (g == 0) ? p1 : (g == 1) ? p2 : (g == 2) ? p3 : p4;   // row end
    int maxd = max(max(p1 - p0, p2 - p1), max(p3 - p2, p4 - p3));  // wave loop bound

    float4 acc = make_float4(0.f, 0.f, 0.f, 0.f);

    if (maxd > 0) {
        long long ev[8];
        load8(ev, edges, sg, eg, 0);
        for (int j = 0; j < maxd; j += 8) {
            long long evn[8];
            if (j + 8 < maxd) load8(evn, edges, sg, eg, j + 8);
            #pragma unroll
            for (int u = 0; u < 8; ++u) {
                int   col = (int)(unsigned)ev[u];
                float v   = __int_as_float((int)(ev[u] >> 32));
                const float* q;
                if (LAYER == 1)
                    q = (col < USER_NUM) ? xu + (size_t)col * EMB : xi + (size_t)(col - USER_NUM) * EMB;
                else
                    q = xu + (size_t)col * EMB;
                float4 gv = ((const float4*)q)[c];
                acc.x += v * gv.x; acc.y += v * gv.y; acc.z += v * gv.z; acc.w += v * gv.w;
            }
            #pragma unroll
            for (int u = 0; u < 8; ++u) ev[u] = evn[u];
        }
    }

    size_t o = (size_t)(r0 + g) * EMB + (size_t)c * 4;
    float4* yp = (float4*)(y + o);
    float4* op = (float4*)(out + o);
    if (LAYER == 1) {
        *yp = acc;
        *op = acc;
    } else if (LAYER == 2) {
        *yp = acc;
        float4 t = *op;
        t.x += acc.x; t.y += acc.y; t.z += acc.z; t.w += acc.w;
        *op = t;
    } else {
        const float s = 1.0f / 3.0f;
        float4 t = *op;
        t.x = (t.x + acc.x) * s; t.y = (t.y + acc.y) * s;
        t.z = (t.z + acc.z) * s; t.w = (t.w + acc.w) * s;
        *op = t;
    }
}

// ===========================================================================
// Fallback (atomic path) in case ws_size is too small for CSR arrays
// ===========================================================================
__global__ void init_kernel(const float* __restrict__ user_emb, const float* __restrict__ item_emb,
                            float* __restrict__ x, float* __restrict__ out) {
    int idx = blockIdx.x * blockDim.x + threadIdx.x;
    const int total = NNODE * EMB / 4;
    if (idx >= total) return;
    const int user_total = USER_NUM * EMB / 4;
    float4 v = (idx < user_total) ? ((const float4*)user_emb)[idx]
                                  : ((const float4*)item_emb)[idx - user_total];
    ((float4*)x)[idx]   = v;
    ((float4*)out)[idx] = make_float4(0.f, 0.f, 0.f, 0.f);
}

__global__ void scatter_kernel(const float* __restrict__ x, float* __restrict__ y,
                               const float* __restrict__ vals, const int* __restrict__ rows,
                               const int* __restrict__ cols, int nnz) {
    int tid = blockIdx.x * blockDim.x + threadIdx.x;
    int e = tid >> 4;
    if (e >= nnz) return;
    int c = tid & 15;
    int r = rows[e], col = cols[e];
    float v = vals[e];
    float4 xv = ((const float4*)(x + (size_t)col * EMB))[c];
    float* dst = y + (size_t)r * EMB + (size_t)c * 4;
    atomicAdd(dst + 0, xv.x * v);
    atomicAdd(dst + 1, xv.y * v);
    atomicAdd(dst + 2, xv.z * v);
    atomicAdd(dst + 3, xv.w * v);
}

__global__ void accum_kernel(float* __restrict__ out, const float* __restrict__ y, float scale) {
    int idx = blockIdx.x * blockDim.x + threadIdx.x;
    const int total = NNODE * EMB / 4;
    if (idx >= total) return;
    float4 o = ((float4*)out)[idx];
    float4 a = ((const float4*)y)[idx];
    o.x = (o.x + a.x) * scale; o.y = (o.y + a.y) * scale;
    o.z = (o.z + a.z) * scale; o.w = (o.w + a.w) * scale;
    ((float4*)out)[idx] = o;
}

extern "C" void kernel_launch(void* const* d_in, const int* in_sizes, int n_in,
                              void* d_out, int out_size, void* d_ws, size_t ws_size,
                              hipStream_t stream) {
    const float* user_emb = (const float*)d_in[0];
    const float* item_emb = (const float*)d_in[1];
    const float* vals     = (const float*)d_in[2];
    const int*   rows     = (const int*)d_in[3];
    const int*   cols     = (const int*)d_in[4];
    const int    nnz      = in_sizes[2];

    float* out = (float*)d_out;

    const size_t embN   = (size_t)NNODE * EMB;        // 7,680,000 floats
    const size_t rp_pad = 120064;                     // NNODE+1 rounded up (8B-align after)

    // Persistent ws layout:
    //   bufA: embN floats | bufB: embN floats | row_ptr: rp_pad ints | edges: nnz int2
    // Build-time aliases (dead before their host buffer is written):
    //   tmp (nnz int2) -> front of bufA; bcounts/bucket_off/bcursor -> front of bufB
    size_t need = (2 * embN + rp_pad) * 4 + (size_t)nnz * 8;

    if (ws_size >= need) {
        float* bufA    = (float*)d_ws;
        float* bufB    = bufA + embN;
        int*   row_ptr = (int*)(bufB + embN);
        int2*  edges   = (int2*)(row_ptr + rp_pad);

        int2* tmp        = (int2*)bufA;
        int*  bcounts    = (int*)bufB;
        int*  bucket_off = bcounts + 512;       // NB+1 used
        int*  bcursor    = bucket_off + 512;

        // --- build CSR (two-pass LDS-binned counting sort) ---
        hipMemsetAsync(bcounts, 0, NB * sizeof(int), stream);
        bucket_hist_kernel<<<256, 256, 0, stream>>>(rows, bcounts, nnz);
        bucket_scan_kernel<<<1, 512, 0, stream>>>(bcounts, bucket_off, bcursor, row_ptr, nnz);
        phase1_kernel<<<(nnz + P1_CHUNK - 1) / P1_CHUNK, 256, 0, stream>>>(rows, cols, vals, bcursor, tmp, nnz);
        phase2_kernel<<<NB, 256, 0, stream>>>(tmp, bucket_off, row_ptr, edges);

        // --- 3 propagation layers, accumulation fused into epilogues ---
        const int nwaves = NNODE / 4;                      // 4 rows per wave
        const int blocks = (nwaves * 64 + 255) / 256;      // 4 waves per block
        spmm_kernel<1><<<blocks, 256, 0, stream>>>(user_emb, item_emb, row_ptr, edges, bufA, out);
        spmm_kernel<2><<<blocks, 256, 0, stream>>>(bufA, nullptr, row_ptr, edges, bufB, out);
        spmm_kernel<3><<<blocks, 256, 0, stream>>>(bufB, nullptr, row_ptr, edges, nullptr, out);
    } else {
        // fallback: atomic scatter path
        float* x = (float*)d_ws;
        float* y = x + embN;
        const size_t emb_bytes = embN * sizeof(float);
        {
            int total = NNODE * EMB / 4;
            init_kernel<<<(total + 255) / 256, 256, 0, stream>>>(user_emb, item_emb, x, out);
        }
        for (int layer = 0; layer < 3; ++layer) {
            hipMemsetAsync(y, 0, emb_bytes, stream);
            long long threads = (long long)nnz * 16;
            scatter_kernel<<<(int)((threads + 255) / 256), 256, 0, stream>>>(x, y, vals, rows, cols, nnz);
            int total = NNODE * EMB / 4;
            accum_kernel<<<(total + 255) / 256, 256, 0, stream>>>(out, y, layer < 2 ? 1.0f : (1.0f / 3.0f));
            float* t = x; x = y; y = t;
        }
    }
}